// Round 5
// baseline (62.601 us; speedup 1.0000x reference)
//
#include <hip/hip_runtime.h>

#define G 64
#define NN 64
#define TT 4096
#define EDGES 131072

#define OUT_ETOT 0
#define OUT_NODEE 64
#define OUT_Q (64 + 4096)
#define OUT_NF (64 + 4096 + 4096)

typedef unsigned long long ull;

__device__ __forceinline__ float wave_sum_f(float v) {
#pragma unroll
    for (int m = 1; m < 64; m <<= 1) v += __shfl_xor(v, m);
    return v;
}
__device__ __forceinline__ double wave_sum_d(double v) {
#pragma unroll
    for (int m = 1; m < 64; m <<= 1) v += __shfl_xor(v, m);
    return v;
}
__device__ __forceinline__ double bcast_d(double v, int j) {
    union { double d; int i[2]; } u;
    u.d = v;
    union { int i[2]; double d; } r;
    r.i[0] = __builtin_amdgcn_readlane(u.i[0], j);
    r.i[1] = __builtin_amdgcn_readlane(u.i[1], j);
    return r.d;
}
__device__ __forceinline__ int type_of(float4 na) {
    int t = 0;
    float best = na.x;
    if (na.y > best) { best = na.y; t = 1; }
    if (na.z > best) { best = na.z; t = 2; }
    if (na.w > best) { best = na.w; t = 3; }
    return t;
}
__device__ __forceinline__ float fcut(float R, float c1) {
    if (R < 1.0f) return c1;           // R is always > 0 here
    if (R > 6.0f) return 0.0f;
    float x = 1.0f - (R - 1.0f) * 0.2f;  // in [0,1]
    float ex = __expf(2.0f * x);
    float t = (ex - 1.0f) / (ex + 1.0f); // tanh(x)
    return t * t * t;
}

// ---- k_scatter: pack (edge_idx | R_bits) so max == last-write-wins by order --
__global__ __launch_bounds__(256) void k_scatter(const int* __restrict__ ei,
                                                 const float* __restrict__ elen,
                                                 ull* __restrict__ packed) {
    int e = blockIdx.x * blockDim.x + threadIdx.x;
    if (e >= EDGES) return;
    int i = ei[e];
    int j = ei[EDGES + e];
    float R = elen[e];                        // in [1,6] -> bits > 0
    ull v = ((ull)(unsigned)e << 32) | (ull)__float_as_uint(R);
    atomicMax(&packed[(i << 6) + (j & 63)], v);
}

// ---- k_solve: per-graph; recompute factor tril from packed; fp64 fwd-sub -----
__global__ __launch_bounds__(256) void k_solve(
    const ull* __restrict__ packed, const float* __restrict__ node_attrs,
    const float* __restrict__ kappa, const float* __restrict__ ref_eta,
    const float* __restrict__ ref_log_sigma, const float* __restrict__ short_e,
    float* __restrict__ qc, float* __restrict__ qsum, float* __restrict__ out) {
    __shared__ float sL[64][65];
    __shared__ float s_sig[64];
    __shared__ float s_diag[64];
    const int g = blockIdx.x;
    const int tid = threadIdx.x;
    const float SQRT_PI = 1.7724538509055159f;

    if (tid < 64) {
        float4 na = *(const float4*)(node_attrs + ((size_t)((g << 6) + tid) << 2));
        int t = type_of(na);
        float sg = __expf(ref_log_sigma[t]);
        s_sig[tid] = sg;
        s_diag[tid] = ref_eta[t] + 1.0f / (sg * SQRT_PI);
    }
    if (tid == 64) out[OUT_ETOT + g] = short_e[g];  // init for k_final atomics
    __syncthreads();

    // recompute factor matrix for this graph's block (coalesced packed reads)
#pragma unroll
    for (int k = 0; k < 16; ++k) {
        int c = k * 256 + tid;  // 0..4095
        int row = c >> 6, col = c & 63;
        ull pk = packed[((size_t)g << 12) + c];
        float R = (pk > 0ull) ? __uint_as_float((unsigned)pk) : 0.5f;
        float sr = s_sig[row], sc = s_sig[col];
        float gam = sqrtf(sr * sr + sc * sc);
        sL[row][col] = erff(R * (0.70710678118654752f / gam)) * __frcp_rn(R);
    }
    __syncthreads();

    if (tid < 64) {
        const int i = tid;
        double Ld = (double)(s_diag[i] + sL[i][i]);
        double inv = 1.0 / Ld;
        double au = 1.0;
        double av = (double)kappa[(g << 6) + i];
        double my_u = 0.0, my_v = 0.0;
        for (int j = 0; j < 64; ++j) {
            double ij = bcast_d(inv, j);
            double uj = bcast_d(au, j) * ij;
            double vj = bcast_d(av, j) * ij;
            if (i == j) { my_u = uj; my_v = vj; }
            if (i > j) {
                double Lij = (double)sL[i][j];
                au -= Lij * uj;
                av -= Lij * vj;
            }
        }
        double Su = wave_sum_d(my_u);
        double Sv = wave_sum_d(my_v);
        double lam = Sv / Su;  // q = -v + (Sv/Su)*u  (ensures sum(q)=0)
        float q = (float)(-my_v + lam * my_u);
        qc[(g << 6) + i] = q;
        float sq = wave_sum_f(q);
        if (i == 0) qsum[g] = sq;
    }
}

// ---- k_final: wave = row; recompute factor/fc; E2b + matvecs + epilogue ------
__global__ __launch_bounds__(256) void k_final(
    const ull* __restrict__ packed, const float* __restrict__ qc,
    const float* __restrict__ qsum, const float* __restrict__ node_attrs,
    const float* __restrict__ ref_log_sigma, const float* __restrict__ ref_A,
    const float* __restrict__ ref_B, const float* __restrict__ ref_C,
    const float* __restrict__ ref_D, const float* __restrict__ ref_mu,
    const float* __restrict__ atomic_short, const float* __restrict__ nf_in,
    float* __restrict__ out) {
    const int i = blockIdx.x * 4 + (threadIdx.x >> 6);  // node / matrix row
    const int lane = threadIdx.x & 63;                  // column
    const int g = i >> 6;
    const int ir = i & 63;
    const float SQRT_PI = 1.7724538509055159f;
    const float th1 = tanhf(1.0f);
    const float c1 = th1 * th1 * th1;
    const float factor_off = erff(0.70710678118654752f / 0.5f) * 2.0f;

    // independent coalesced loads
    const ull pk = packed[((size_t)i << 6) + lane];
    const float qj = qc[(g << 6) + lane];
    const float qs = qsum[lane];
    const float2 v2 = ((const float2*)nf_in)[(i << 6) + lane];
    const float4 na = *(const float4*)(node_attrs + ((size_t)((g << 6) + lane) << 2));

    const int tj = type_of(na);
    const int ti = __shfl(tj, ir);
    const float sgj = __expf(ref_log_sigma[tj]);
    const float sgi = __shfl(sgj, ir);   // own-row sigma, uniform across wave
    const float gam = sqrtf(sgi * sgi + sgj * sgj);

    const float R = (pk > 0ull) ? __uint_as_float((unsigned)pk) : 0.5f;
    const float rinv = __frcp_rn(R);
    const float factor = erff(R * (0.70710678118654752f / gam)) * rinv;
    const float fc = fcut(R, c1);

    float e = 0.0f;
    if (ir != lane) {
        int t4 = ti * 4 + tj;
        float r2 = rinv * rinv;
        float r6 = r2 * r2 * r2;
        e = (ref_A[t4] * __expf(ref_B[t4] * (ref_mu[t4] - R)) - ref_C[t4] * r6 -
             ref_D[t4] * (r6 * r2)) * fc;
    }
    float p = factor * fc * qj;
    float w = factor * qj;
#pragma unroll
    for (int m = 1; m < 64; m <<= 1) {  // 3 interleaved butterflies
        p += __shfl_xor(p, m);
        w += __shfl_xor(w, m);
        e += __shfl_xor(e, m);
    }
    const float Qall = wave_sum_f(qs);
    const float qsg = __shfl(qs, g);    // qsum[g]
    const float q = __shfl(qj, ir);     // qc[i]

    // feats copy: 2 floats/lane into the stride-130 row
    *(float2*)(out + OUT_NF + (size_t)i * 130 + lane * 2) = v2;

    if (lane == 0) {
        float off = Qall - qsg;
        float aE2b = 0.5f * e;
        float coef = 0.5f / (sgi * SQRT_PI);
        float ap = p + factor_off * c1 * off;
        float V = w + factor_off * off + coef * q;
        float aEel = q * V;
        out[OUT_NODEE + i] = aEel + aE2b + atomic_short[i];
        out[OUT_Q + i] = q;
        out[OUT_NF + (size_t)i * 130 + 128] = q;
        out[OUT_NF + (size_t)i * 130 + 129] = ap;
        atomicAdd(&out[OUT_ETOT + g], aEel + aE2b);
    }
}

extern "C" void kernel_launch(void* const* d_in, const int* in_sizes, int n_in,
                              void* d_out, int out_size, void* d_ws, size_t ws_size,
                              hipStream_t stream) {
    const float* node_attrs = (const float*)d_in[1];
    const int* edge_index = (const int*)d_in[2];
    const float* edge_length = (const float*)d_in[3];
    const float* kappa = (const float*)d_in[4];
    const float* node_feats = (const float*)d_in[5];
    const float* ref_eta = (const float*)d_in[6];
    const float* ref_log_sigma = (const float*)d_in[7];
    const float* ref_A = (const float*)d_in[8];
    const float* ref_B = (const float*)d_in[9];
    const float* ref_C = (const float*)d_in[10];
    const float* ref_D = (const float*)d_in[11];
    const float* ref_mu = (const float*)d_in[12];
    const float* short_energy = (const float*)d_in[13];
    const float* atomic_short = (const float*)d_in[14];

    float* out = (float*)d_out;
    char* ws = (char*)d_ws;
    ull* packed = (ull*)ws;                     // TT*64*8 = 2 MiB
    float* qc = (float*)(ws + (2u << 20));      // 16 KiB
    float* qsum = qc + TT;                      // 256 B

    hipMemsetAsync(packed, 0, (size_t)TT * 64 * sizeof(ull), stream);
    k_scatter<<<EDGES / 256, 256, 0, stream>>>(edge_index, edge_length, packed);
    k_solve<<<G, 256, 0, stream>>>(packed, node_attrs, kappa, ref_eta,
                                   ref_log_sigma, short_energy, qc, qsum, out);
    k_final<<<TT / 4, 256, 0, stream>>>(packed, qc, qsum, node_attrs,
                                        ref_log_sigma, ref_A, ref_B, ref_C,
                                        ref_D, ref_mu, atomic_short, node_feats,
                                        out);
}

// Round 6
// 40.291 us; speedup vs baseline: 1.5537x; 1.5537x over previous
//
#include <hip/hip_runtime.h>

#define G 64
#define NN 64
#define TT 4096
#define EDGES 131072

#define OUT_ETOT 0
#define OUT_NODEE 64
#define OUT_Q (64 + 4096)
#define OUT_NF (64 + 4096 + 4096)

typedef unsigned long long ull;

__device__ __forceinline__ float wave_sum_f(float v) {
#pragma unroll
    for (int m = 1; m < 64; m <<= 1) v += __shfl_xor(v, m);
    return v;
}
__device__ __forceinline__ double wave_sum_d(double v) {
#pragma unroll
    for (int m = 1; m < 64; m <<= 1) v += __shfl_xor(v, m);
    return v;
}
__device__ __forceinline__ double bcast_d(double v, int j) {
    union { double d; int i[2]; } u;
    u.d = v;
    union { int i[2]; double d; } r;
    r.i[0] = __builtin_amdgcn_readlane(u.i[0], j);
    r.i[1] = __builtin_amdgcn_readlane(u.i[1], j);
    return r.d;
}
__device__ __forceinline__ int type_of(float4 na) {
    int t = 0;
    float best = na.x;
    if (na.y > best) { best = na.y; t = 1; }
    if (na.z > best) { best = na.z; t = 2; }
    if (na.w > best) { best = na.w; t = 3; }
    return t;
}
__device__ __forceinline__ float fcut(float R, float c1) {
    if (R < 1.0f) return c1;             // R is always > 0 here
    if (R > 6.0f) return 0.0f;
    float x = 1.0f - (R - 1.0f) * 0.2f;  // in [0,1]
    float ex = __expf(2.0f * x);
    float t = (ex - 1.0f) / (ex + 1.0f); // tanh(x)
    return t * t * t;
}

// ---- k_fill: fast 2 MiB zero (replaces slow in-graph hipMemsetAsync) ---------
__global__ __launch_bounds__(256) void k_fill(ulonglong2* __restrict__ p) {
    int idx = blockIdx.x * blockDim.x + threadIdx.x;  // 131072 x 16B = 2 MiB
    p[idx] = make_ulonglong2(0ull, 0ull);
}

// ---- k_scatter: pack (edge_idx | R_bits) so max == last-write-wins by order --
__global__ __launch_bounds__(256) void k_scatter(const int* __restrict__ ei,
                                                 const float* __restrict__ elen,
                                                 ull* __restrict__ packed) {
    int e = blockIdx.x * blockDim.x + threadIdx.x;
    if (e >= EDGES) return;
    int i = ei[e];
    int j = ei[EDGES + e];
    float R = elen[e];                        // in [1,6] -> bits > 0
    ull v = ((ull)(unsigned)e << 32) | (ull)__float_as_uint(R);
    atomicMax(&packed[(i << 6) + (j & 63)], v);
}

// ---- k_solve: per-graph; recompute factor tril from packed; fp64 fwd-sub -----
__global__ __launch_bounds__(256) void k_solve(
    const ull* __restrict__ packed, const float* __restrict__ node_attrs,
    const float* __restrict__ kappa, const float* __restrict__ ref_eta,
    const float* __restrict__ ref_log_sigma, const float* __restrict__ short_e,
    float* __restrict__ qc, float* __restrict__ qsum, float* __restrict__ out) {
    __shared__ float sL[64][65];
    __shared__ float s_sig[64];
    __shared__ float s_diag[64];
    const int g = blockIdx.x;
    const int tid = threadIdx.x;
    const float SQRT_PI = 1.7724538509055159f;

    if (tid < 64) {
        float4 na = *(const float4*)(node_attrs + ((size_t)((g << 6) + tid) << 2));
        int t = type_of(na);
        float sg = __expf(ref_log_sigma[t]);
        s_sig[tid] = sg;
        s_diag[tid] = ref_eta[t] + 1.0f / (sg * SQRT_PI);
    }
    if (tid == 64) out[OUT_ETOT + g] = short_e[g];  // init for k_final atomics
    __syncthreads();

    // recompute factor matrix for this graph's block (coalesced packed reads)
#pragma unroll
    for (int k = 0; k < 16; ++k) {
        int c = k * 256 + tid;  // 0..4095
        int row = c >> 6, col = c & 63;
        ull pk = packed[((size_t)g << 12) + c];
        float R = (pk > 0ull) ? __uint_as_float((unsigned)pk) : 0.5f;
        float sr = s_sig[row], sc = s_sig[col];
        float gam = sqrtf(sr * sr + sc * sc);
        sL[row][col] = erff(R * (0.70710678118654752f / gam)) * __frcp_rn(R);
    }
    __syncthreads();

    if (tid < 64) {
        const int i = tid;
        double Ld = (double)(s_diag[i] + sL[i][i]);
        double inv = 1.0 / Ld;
        double au = 1.0;
        double av = (double)kappa[(g << 6) + i];
        double my_u = 0.0, my_v = 0.0;
        for (int j = 0; j < 64; ++j) {
            double ij = bcast_d(inv, j);
            double uj = bcast_d(au, j) * ij;
            double vj = bcast_d(av, j) * ij;
            if (i == j) { my_u = uj; my_v = vj; }
            if (i > j) {
                double Lij = (double)sL[i][j];
                au -= Lij * uj;
                av -= Lij * vj;
            }
        }
        double Su = wave_sum_d(my_u);
        double Sv = wave_sum_d(my_v);
        double lam = Sv / Su;  // q = -v + (Sv/Su)*u  (ensures sum(q)=0)
        float q = (float)(-my_v + lam * my_u);
        qc[(g << 6) + i] = q;
        float sq = wave_sum_f(q);
        if (i == 0) qsum[g] = sq;
    }
}

// ---- k_final: wave = row; recompute factor/fc; E2b + matvecs + epilogue ------
__global__ __launch_bounds__(256) void k_final(
    const ull* __restrict__ packed, const float* __restrict__ qc,
    const float* __restrict__ qsum, const float* __restrict__ node_attrs,
    const float* __restrict__ ref_log_sigma, const float* __restrict__ ref_A,
    const float* __restrict__ ref_B, const float* __restrict__ ref_C,
    const float* __restrict__ ref_D, const float* __restrict__ ref_mu,
    const float* __restrict__ atomic_short, const float* __restrict__ nf_in,
    float* __restrict__ out) {
    __shared__ float s_red[4];
    const int wv = threadIdx.x >> 6;
    const int i = blockIdx.x * 4 + wv;                  // node / matrix row
    const int lane = threadIdx.x & 63;                  // column
    const int g = i >> 6;                               // uniform per block
    const int ir = i & 63;
    const float SQRT_PI = 1.7724538509055159f;
    const float th1 = tanhf(1.0f);
    const float c1 = th1 * th1 * th1;
    const float factor_off = erff(0.70710678118654752f / 0.5f) * 2.0f;

    // independent coalesced loads
    const ull pk = packed[((size_t)i << 6) + lane];
    const float qj = qc[(g << 6) + lane];
    const float qs = qsum[lane];
    const float2 v2 = ((const float2*)nf_in)[(i << 6) + lane];
    const float4 na = *(const float4*)(node_attrs + ((size_t)((g << 6) + lane) << 2));

    const int tj = type_of(na);
    const int ti = __shfl(tj, ir);
    const float sgj = __expf(ref_log_sigma[tj]);
    const float sgi = __shfl(sgj, ir);   // own-row sigma, uniform across wave
    const float gam = sqrtf(sgi * sgi + sgj * sgj);

    const float R = (pk > 0ull) ? __uint_as_float((unsigned)pk) : 0.5f;
    const float rinv = __frcp_rn(R);
    const float factor = erff(R * (0.70710678118654752f / gam)) * rinv;
    const float fc = fcut(R, c1);

    float e = 0.0f;
    if (ir != lane) {
        int t4 = ti * 4 + tj;
        float r2 = rinv * rinv;
        float r6 = r2 * r2 * r2;
        e = (ref_A[t4] * __expf(ref_B[t4] * (ref_mu[t4] - R)) - ref_C[t4] * r6 -
             ref_D[t4] * (r6 * r2)) * fc;
    }
    float p = factor * fc * qj;
    float w = factor * qj;
#pragma unroll
    for (int m = 1; m < 64; m <<= 1) {  // 3 interleaved butterflies
        p += __shfl_xor(p, m);
        w += __shfl_xor(w, m);
        e += __shfl_xor(e, m);
    }
    const float Qall = wave_sum_f(qs);
    const float qsg = __shfl(qs, g);    // qsum[g]
    const float q = __shfl(qj, ir);     // qc[i]

    // feats copy: 2 floats/lane into the stride-130 row
    *(float2*)(out + OUT_NF + (size_t)i * 130 + lane * 2) = v2;

    if (lane == 0) {
        float off = Qall - qsg;
        float aE2b = 0.5f * e;
        float coef = 0.5f / (sgi * SQRT_PI);
        float ap = p + factor_off * c1 * off;
        float V = w + factor_off * off + coef * q;
        float aEel = q * V;
        out[OUT_NODEE + i] = aEel + aE2b + atomic_short[i];
        out[OUT_Q + i] = q;
        out[OUT_NF + (size_t)i * 130 + 128] = q;
        out[OUT_NF + (size_t)i * 130 + 129] = ap;
        s_red[wv] = aEel + aE2b;
    }
    __syncthreads();
    if (threadIdx.x == 0) {
        // one atomic per block (4 nodes, same graph) instead of 4
        atomicAdd(&out[OUT_ETOT + g],
                  s_red[0] + s_red[1] + s_red[2] + s_red[3]);
    }
}

extern "C" void kernel_launch(void* const* d_in, const int* in_sizes, int n_in,
                              void* d_out, int out_size, void* d_ws, size_t ws_size,
                              hipStream_t stream) {
    const float* node_attrs = (const float*)d_in[1];
    const int* edge_index = (const int*)d_in[2];
    const float* edge_length = (const float*)d_in[3];
    const float* kappa = (const float*)d_in[4];
    const float* node_feats = (const float*)d_in[5];
    const float* ref_eta = (const float*)d_in[6];
    const float* ref_log_sigma = (const float*)d_in[7];
    const float* ref_A = (const float*)d_in[8];
    const float* ref_B = (const float*)d_in[9];
    const float* ref_C = (const float*)d_in[10];
    const float* ref_D = (const float*)d_in[11];
    const float* ref_mu = (const float*)d_in[12];
    const float* short_energy = (const float*)d_in[13];
    const float* atomic_short = (const float*)d_in[14];

    float* out = (float*)d_out;
    char* ws = (char*)d_ws;
    ull* packed = (ull*)ws;                     // TT*64*8 = 2 MiB
    float* qc = (float*)(ws + (2u << 20));      // 16 KiB
    float* qsum = qc + TT;                      // 256 B

    k_fill<<<512, 256, 0, stream>>>((ulonglong2*)packed);
    k_scatter<<<EDGES / 256, 256, 0, stream>>>(edge_index, edge_length, packed);
    k_solve<<<G, 256, 0, stream>>>(packed, node_attrs, kappa, ref_eta,
                                   ref_log_sigma, short_energy, qc, qsum, out);
    k_final<<<TT / 4, 256, 0, stream>>>(packed, qc, qsum, node_attrs,
                                        ref_log_sigma, ref_A, ref_B, ref_C,
                                        ref_D, ref_mu, atomic_short, node_feats,
                                        out);
}

// Round 7
// 38.065 us; speedup vs baseline: 1.6446x; 1.0585x over previous
//
#include <hip/hip_runtime.h>

#define G 64
#define NN 64
#define TT 4096
#define EDGES 131072

#define OUT_ETOT 0
#define OUT_NODEE 64
#define OUT_Q (64 + 4096)
#define OUT_NF (64 + 4096 + 4096)

typedef unsigned long long ull;

__device__ __forceinline__ float wave_sum_f(float v) {
#pragma unroll
    for (int m = 1; m < 64; m <<= 1) v += __shfl_xor(v, m);
    return v;
}
__device__ __forceinline__ double wave_sum_d(double v) {
#pragma unroll
    for (int m = 1; m < 64; m <<= 1) v += __shfl_xor(v, m);
    return v;
}
__device__ __forceinline__ double bcast_d(double v, int j) {
    union { double d; int i[2]; } u;
    u.d = v;
    union { int i[2]; double d; } r;
    r.i[0] = __builtin_amdgcn_readlane(u.i[0], j);
    r.i[1] = __builtin_amdgcn_readlane(u.i[1], j);
    return r.d;
}
__device__ __forceinline__ int type_of(float4 na) {
    int t = 0;
    float best = na.x;
    if (na.y > best) { best = na.y; t = 1; }
    if (na.z > best) { best = na.z; t = 2; }
    if (na.w > best) { best = na.w; t = 3; }
    return t;
}
__device__ __forceinline__ float fcut(float R, float c1) {
    if (R < 1.0f) return c1;             // R is always > 0 here
    if (R > 6.0f) return 0.0f;
    float x = 1.0f - (R - 1.0f) * 0.2f;  // in [0,1]
    float ex = __expf(2.0f * x);
    float t = (ex - 1.0f) / (ex + 1.0f); // tanh(x)
    return t * t * t;
}

// ---- k_fill: fast 2 MiB zero of packed ---------------------------------------
__global__ __launch_bounds__(256) void k_fill(ulonglong2* __restrict__ p) {
    int idx = blockIdx.x * blockDim.x + threadIdx.x;  // 131072 x 16B = 2 MiB
    p[idx] = make_ulonglong2(0ull, 0ull);
}

// ---- k_scatter: pack (edge_idx | R_bits) so max == last-write-wins by order --
__global__ __launch_bounds__(256) void k_scatter(const int* __restrict__ ei,
                                                 const float* __restrict__ elen,
                                                 ull* __restrict__ packed) {
    int e = blockIdx.x * blockDim.x + threadIdx.x;
    if (e >= EDGES) return;
    int i = ei[e];
    int j = ei[EDGES + e];
    float R = elen[e];                        // in [1,6] -> bits > 0
    ull v = ((ull)(unsigned)e << 32) | (ull)__float_as_uint(R);
    atomicMax(&packed[(i << 6) + (j & 63)], v);
}

// ---- k_build: full-chip TLP; all transcendentals; wave = row, lane = col -----
__global__ __launch_bounds__(256) void k_build(
    const ull* __restrict__ packed, const float* __restrict__ node_attrs,
    const float* __restrict__ ref_log_sigma, const float* __restrict__ ref_A,
    const float* __restrict__ ref_B, const float* __restrict__ ref_C,
    const float* __restrict__ ref_D, const float* __restrict__ ref_mu,
    float* __restrict__ factor_g, float* __restrict__ fcf_g,
    float* __restrict__ aE2b) {
    const int row = blockIdx.x * 4 + (threadIdx.x >> 6);  // node i
    const int lane = threadIdx.x & 63;                    // column j
    const int g = row >> 6;
    const int ir = row & 63;
    const float th1 = tanhf(1.0f);
    const float c1 = th1 * th1 * th1;

    // independent coalesced loads (no dependent gather: R comes from packed)
    const ull pk = packed[((size_t)row << 6) + lane];
    const float4 na = *(const float4*)(node_attrs + ((size_t)((g << 6) + lane) << 2));

    const int tj = type_of(na);
    const int ti = __shfl(tj, ir);
    const float sgj = __expf(ref_log_sigma[tj]);
    const float sgi = __shfl(sgj, ir);
    const float gam = sqrtf(sgi * sgi + sgj * sgj);

    const float R = (pk > 0ull) ? __uint_as_float((unsigned)pk) : 0.5f;
    const float rinv = __frcp_rn(R);
    const float factor = erff(R * (0.70710678118654752f / gam)) * rinv;
    const float fc = fcut(R, c1);

    factor_g[((size_t)row << 6) + lane] = factor;
    fcf_g[((size_t)row << 6) + lane] = factor * fc;

    float e = 0.0f;
    if (ir != lane) {
        int t4 = ti * 4 + tj;
        float r2 = rinv * rinv;
        float r6 = r2 * r2 * r2;
        e = (ref_A[t4] * __expf(ref_B[t4] * (ref_mu[t4] - R)) - ref_C[t4] * r6 -
             ref_D[t4] * (r6 * r2)) * fc;
    }
    e = wave_sum_f(e);
    if (lane == 0) aE2b[row] = 0.5f * e;
}

// ---- k_solve: lightweight per-graph fp64 dual forward substitution -----------
__global__ __launch_bounds__(256) void k_solve(
    const float* __restrict__ factor_g, const float* __restrict__ node_attrs,
    const float* __restrict__ kappa, const float* __restrict__ ref_eta,
    const float* __restrict__ ref_log_sigma, const float* __restrict__ short_e,
    float* __restrict__ qc, float* __restrict__ qsum, float* __restrict__ out) {
    __shared__ float sL[64][65];
    __shared__ float s_diag[64];
    const int g = blockIdx.x;
    const int tid = threadIdx.x;
    const float SQRT_PI = 1.7724538509055159f;

    // stage 16 KB factor block into LDS, coalesced float4
    const float4* src4 = (const float4*)(factor_g + ((size_t)g << 12));
#pragma unroll
    for (int k = 0; k < 4; ++k) {
        int f = k * 256 + tid;          // float4 index 0..1023
        float4 v = src4[f];
        int rr = f >> 4, cc = (f & 15) << 2;
        sL[rr][cc] = v.x; sL[rr][cc + 1] = v.y;
        sL[rr][cc + 2] = v.z; sL[rr][cc + 3] = v.w;
    }
    if (tid < 64) {
        float4 na = *(const float4*)(node_attrs + ((size_t)((g << 6) + tid) << 2));
        int t = type_of(na);
        float sg = __expf(ref_log_sigma[t]);
        s_diag[tid] = ref_eta[t] + 1.0f / (sg * SQRT_PI);
    }
    if (tid == 64) out[OUT_ETOT + g] = short_e[g];  // init for k_final atomics
    __syncthreads();

    if (tid < 64) {
        const int i = tid;
        double Ld = (double)(s_diag[i] + sL[i][i]);
        double inv = 1.0 / Ld;
        double au = 1.0;
        double av = (double)kappa[(g << 6) + i];
        double my_u = 0.0, my_v = 0.0;
        for (int j = 0; j < 64; ++j) {
            double ij = bcast_d(inv, j);
            double uj = bcast_d(au, j) * ij;
            double vj = bcast_d(av, j) * ij;
            if (i == j) { my_u = uj; my_v = vj; }
            if (i > j) {
                double Lij = (double)sL[i][j];
                au -= Lij * uj;
                av -= Lij * vj;
            }
        }
        double Su = wave_sum_d(my_u);
        double Sv = wave_sum_d(my_v);
        double lam = Sv / Su;  // q = -v + (Sv/Su)*u  (ensures sum(q)=0)
        float q = (float)(-my_v + lam * my_u);
        qc[(g << 6) + i] = q;
        float sq = wave_sum_f(q);
        if (i == 0) qsum[g] = sq;
    }
}

// ---- k_final: wave = row; matvecs from precomputed mats + epilogue -----------
__global__ __launch_bounds__(256) void k_final(
    const float* __restrict__ factor_g, const float* __restrict__ fcf_g,
    const float* __restrict__ qc, const float* __restrict__ qsum,
    const float* __restrict__ aE2b, const float* __restrict__ node_attrs,
    const float* __restrict__ ref_log_sigma,
    const float* __restrict__ atomic_short, const float* __restrict__ nf_in,
    float* __restrict__ out) {
    __shared__ float s_red[4];
    const int wv = threadIdx.x >> 6;
    const int i = blockIdx.x * 4 + wv;                  // node / matrix row
    const int lane = threadIdx.x & 63;                  // column
    const int g = i >> 6;                               // uniform per block
    const int ir = i & 63;
    const float SQRT_PI = 1.7724538509055159f;
    const float th1 = tanhf(1.0f);
    const float c1 = th1 * th1 * th1;
    const float factor_off = erff(0.70710678118654752f / 0.5f) * 2.0f;

    // independent coalesced loads
    const float f = factor_g[((size_t)i << 6) + lane];
    const float fcf = fcf_g[((size_t)i << 6) + lane];
    const float qj = qc[(g << 6) + lane];
    const float qs = qsum[lane];
    const float2 v2 = ((const float2*)nf_in)[(i << 6) + lane];
    const float4 na = *(const float4*)(node_attrs + ((size_t)((g << 6) + lane) << 2));

    const int tj = type_of(na);
    const float sgj = __expf(ref_log_sigma[tj]);
    const float sgi = __shfl(sgj, ir);   // own-row sigma, uniform across wave

    float p = fcf * qj;
    float w = f * qj;
#pragma unroll
    for (int m = 1; m < 64; m <<= 1) {  // interleaved butterflies
        p += __shfl_xor(p, m);
        w += __shfl_xor(w, m);
    }
    const float Qall = wave_sum_f(qs);
    const float qsg = __shfl(qs, g);    // qsum[g]
    const float q = __shfl(qj, ir);     // qc[i]

    // feats copy: 2 floats/lane into the stride-130 row
    *(float2*)(out + OUT_NF + (size_t)i * 130 + lane * 2) = v2;

    if (lane == 0) {
        float off = Qall - qsg;
        float e2 = aE2b[i];
        float coef = 0.5f / (sgi * SQRT_PI);
        float ap = p + factor_off * c1 * off;
        float V = w + factor_off * off + coef * q;
        float aEel = q * V;
        out[OUT_NODEE + i] = aEel + e2 + atomic_short[i];
        out[OUT_Q + i] = q;
        out[OUT_NF + (size_t)i * 130 + 128] = q;
        out[OUT_NF + (size_t)i * 130 + 129] = ap;
        s_red[wv] = aEel + e2;
    }
    __syncthreads();
    if (threadIdx.x == 0) {
        // one atomic per block (4 nodes, same graph) instead of 4
        atomicAdd(&out[OUT_ETOT + g],
                  s_red[0] + s_red[1] + s_red[2] + s_red[3]);
    }
}

extern "C" void kernel_launch(void* const* d_in, const int* in_sizes, int n_in,
                              void* d_out, int out_size, void* d_ws, size_t ws_size,
                              hipStream_t stream) {
    const float* node_attrs = (const float*)d_in[1];
    const int* edge_index = (const int*)d_in[2];
    const float* edge_length = (const float*)d_in[3];
    const float* kappa = (const float*)d_in[4];
    const float* node_feats = (const float*)d_in[5];
    const float* ref_eta = (const float*)d_in[6];
    const float* ref_log_sigma = (const float*)d_in[7];
    const float* ref_A = (const float*)d_in[8];
    const float* ref_B = (const float*)d_in[9];
    const float* ref_C = (const float*)d_in[10];
    const float* ref_D = (const float*)d_in[11];
    const float* ref_mu = (const float*)d_in[12];
    const float* short_energy = (const float*)d_in[13];
    const float* atomic_short = (const float*)d_in[14];

    float* out = (float*)d_out;
    char* ws = (char*)d_ws;
    ull* packed = (ull*)ws;                     // TT*64*8 = 2 MiB
    float* factor_g = (float*)(ws + (2u << 20));  // 1 MiB
    float* fcf_g = factor_g + (size_t)TT * 64;    // 1 MiB
    float* aE2b = fcf_g + (size_t)TT * 64;
    float* qc = aE2b + TT;
    float* qsum = qc + TT;

    k_fill<<<512, 256, 0, stream>>>((ulonglong2*)packed);
    k_scatter<<<EDGES / 256, 256, 0, stream>>>(edge_index, edge_length, packed);
    k_build<<<TT / 4, 256, 0, stream>>>(packed, node_attrs, ref_log_sigma,
                                        ref_A, ref_B, ref_C, ref_D, ref_mu,
                                        factor_g, fcf_g, aE2b);
    k_solve<<<G, 256, 0, stream>>>(factor_g, node_attrs, kappa, ref_eta,
                                   ref_log_sigma, short_energy, qc, qsum, out);
    k_final<<<TT / 4, 256, 0, stream>>>(factor_g, fcf_g, qc, qsum, aE2b,
                                        node_attrs, ref_log_sigma, atomic_short,
                                        node_feats, out);
}